// Round 4
// baseline (549.779 us; speedup 1.0000x reference)
//
#include <hip/hip_runtime.h>
#include <math.h>

// SimpleRetention bf16-MFMA pipeline, round 4.
// out = (softmax(QK^T) * gamma^|n-m|) @ V ; Q/K = xpos(X@W), V = X@Wv
// B=8 L=2048 H=Dh=1024.
//
// Round-4 changes vs round-3:
//  - gemm128 core: 32x32x16 MFMA (fewer issue slots, +15% MFMA rate)
//  - incremental per-thread staging pointers (kills 64-bit addr recompute VALU)
//
// ws layout (161MB total; phase-aliased):
//   [0,64MB)    Wmat bf16 [8][2048][2048]   (phase2; aliases Xb+WT of phase1)
//   [0,32MB)    Xb  bf16 [16384][1024]      (phase1)
//   [32,38MB)   WT  bf16 [3][1024][1024]    (phase1, W transposed)
//   [64,96MB)   Qb  bf16 [16384][1024]
//   [96,128MB)  Kb  bf16 [16384][1024]
//   [128,160MB) Vt  bf16 [8][1024][2048]    (V transposed per batch)
//   [160,161MB) Zp  f32  [8][16][2048]      (softmax denom partials)

#define LDIM 2048
#define HDIM 1024
#define MTOT 16384

typedef unsigned short u16;
typedef __attribute__((ext_vector_type(16))) float f32x16;
typedef __attribute__((ext_vector_type(8))) short s16x8;

#define GLD16(gp, lp) __builtin_amdgcn_global_load_lds( \
    (const __attribute__((address_space(1))) void*)(gp), \
    (__attribute__((address_space(3))) void*)(lp), 16, 0, 0)

__device__ __forceinline__ u16 f2bf(float f) {
    unsigned u = __float_as_uint(f);
    return (u16)((u + 0x7FFFu + ((u >> 16) & 1u)) >> 16);
}

// sin/cos(ang) via f64 revolution reduction + HW v_sin/v_cos (rev input).
__device__ __forceinline__ void sincos_rev(float ang, float* sn, float* cs) {
    double dr = (double)ang * 0.15915494309189535;   // 1/(2*pi)
    dr -= __builtin_floor(dr);
    float fr = (float)dr;
    float s_, c_;
    asm("v_sin_f32 %0, %1" : "=v"(s_) : "v"(fr));
    asm("v_cos_f32 %0, %1" : "=v"(c_) : "v"(fr));
    *sn = s_; *cs = c_;
}

// C/D mapping for mfma_f32_32x32x16_bf16 (HW-verified m74/m101):
//   col = lane&31, row = (reg&3) + 8*(reg>>2) + 4*(lane>>5), reg in [0,16)
#define ROW32(reg, laneHi) (((reg) & 3) + 8 * ((reg) >> 2) + 4 * (laneHi))

// ---------------------------------------------------------------------------
// Shared 128x128 bf16 MFMA GEMM core. C = A x B^T, A:[*,lda], B:[*,ldb] rowmaj.
// 256 thr = 4 waves (2x2), each wave 64x64 = 2x2 frags of 32x32x16 MFMA.
// LDS: As[128][64] + Bs[128][64] bf16 = 32KB.
// ---------------------------------------------------------------------------
__device__ __forceinline__ void gemm128(const u16* __restrict__ A, const u16* __restrict__ B,
                                        int lda, int ldb, int K, int m0, int n0,
                                        char* smem, int tid, f32x16 (*acc)[2])
{
    u16* As = (u16*)smem;
    u16* Bs = As + 128 * 64;
    const int wv = tid >> 6, ln = tid & 63;
    const int wm = wv >> 1, wn = wv & 1;
    const int lane31 = ln & 31, laneHi = ln >> 5;
    const int srow = wv * 8 + (ln >> 3);   // staging row within 32-row group
    const int scol = (ln & 7) * 8;         // staging col (elements)

    // incremental per-thread global source pointers (advance 64 elems/iter)
    const u16* ap[4];
    const u16* bp[4];
#pragma unroll
    for (int i = 0; i < 4; ++i) {
        ap[i] = A + (size_t)(m0 + i * 32 + srow) * lda + scol;
        bp[i] = B + (size_t)(n0 + i * 32 + srow) * ldb + scol;
    }

    // LDS fragment base offsets (elements); per-kstep adds a constant imm
    int abase[2], bbase[2];
#pragma unroll
    for (int f = 0; f < 2; ++f) {
        abase[f] = (wm * 64 + f * 32 + lane31) * 64 + laneHi * 8;
        bbase[f] = (wn * 64 + f * 32 + lane31) * 64 + laneHi * 8;
    }

    for (int k0 = 0; k0 < K; k0 += 64) {
        __syncthreads();   // all waves done reading previous tile
#pragma unroll
        for (int i = 0; i < 4; ++i) {
            GLD16(ap[i], (char*)As + (i * 32 + wv * 8) * 128);
            GLD16(bp[i], (char*)Bs + (i * 32 + wv * 8) * 128);
            ap[i] += 64; bp[i] += 64;
        }
        __syncthreads();   // tile resident
#pragma unroll
        for (int ks = 0; ks < 4; ++ks) {
            s16x8 af[2], bf[2];
#pragma unroll
            for (int f = 0; f < 2; ++f) {
                af[f] = *(const s16x8*)(As + abase[f] + ks * 16);
                bf[f] = *(const s16x8*)(Bs + bbase[f] + ks * 16);
            }
#pragma unroll
            for (int i = 0; i < 2; ++i)
#pragma unroll
                for (int j = 0; j < 2; ++j)
                    acc[i][j] = __builtin_amdgcn_mfma_f32_32x32x16_bf16(af[i], bf[j], acc[i][j], 0, 0, 0);
        }
    }
    __syncthreads();   // safe to reuse smem in epilogue
}

// ---------------------------------------------------------------------------
// prep: X -> bf16
// ---------------------------------------------------------------------------
__global__ __launch_bounds__(256) void cast_x(const float* __restrict__ X,
                                              u16* __restrict__ Xb, int n4)
{
    int i = blockIdx.x * 256 + threadIdx.x;
    const int stride = gridDim.x * 256;
    for (; i < n4; i += stride) {
        float4 v = ((const float4*)X)[i];
        ushort4 o = make_ushort4(f2bf(v.x), f2bf(v.y), f2bf(v.z), f2bf(v.w));
        ((ushort4*)Xb)[i] = o;
    }
}

// ---------------------------------------------------------------------------
// prep: W (1024x1024 f32, [k][n]) -> WT bf16 [n][k], for z in {Q,K,V}
// ---------------------------------------------------------------------------
__global__ __launch_bounds__(256) void transw(const float* __restrict__ Wq,
                                              const float* __restrict__ Wk,
                                              const float* __restrict__ Wv,
                                              u16* __restrict__ WT)
{
    __shared__ float L[64][65];
    const int z = blockIdx.z;
    const float* Wz = (z == 0) ? Wq : (z == 1) ? Wk : Wv;
    u16* Oz = WT + (size_t)z * HDIM * HDIM;
    const int k0 = blockIdx.y * 64, n0 = blockIdx.x * 64;
    const int t = threadIdx.x;
    const int r_ = t >> 4, c4 = (t & 15) * 4;
#pragma unroll
    for (int it = 0; it < 4; ++it) {
        const int row = it * 16 + r_;
        float4 v = *(const float4*)&Wz[(size_t)(k0 + row) * HDIM + n0 + c4];
        L[row][c4 + 0] = v.x; L[row][c4 + 1] = v.y;
        L[row][c4 + 2] = v.z; L[row][c4 + 3] = v.w;
    }
    __syncthreads();
#pragma unroll
    for (int it = 0; it < 4; ++it) {
        const int orow = it * 16 + r_;   // n-local
        ushort4 o = make_ushort4(f2bf(L[c4 + 0][orow]), f2bf(L[c4 + 1][orow]),
                                 f2bf(L[c4 + 2][orow]), f2bf(L[c4 + 3][orow]));
        *(ushort4*)&Oz[(size_t)(n0 + orow) * HDIM + k0 + c4] = o;
    }
}

// ---------------------------------------------------------------------------
// K1: {Q,K,V} = X@W, xpos fused (fp32) for Q/K, V stored transposed.
// 1D grid 3072, XCD-chunked. decode: xcd(8) | mh(2) n(8) z(3) m8(8)
// ---------------------------------------------------------------------------
__global__ __launch_bounds__(256) void qkv_gemm(
    const u16* __restrict__ Xb, const u16* __restrict__ WT,
    u16* __restrict__ Qb, u16* __restrict__ Kb, u16* __restrict__ Vt)
{
    __shared__ __align__(16) char smem[128 * 136 * 2];
    const int bid = blockIdx.x;
    const int xcd = bid & 7, t = bid >> 3;   // t in [0,384)
    const int m8 = t & 7;
    const int u_ = t >> 3;                   // [0,48)
    const int z  = u_ % 3;
    const int v_ = u_ / 3;                   // [0,16)
    const int n_ = v_ & 7;
    const int mh = v_ >> 3;
    const int m0 = (xcd * 16 + mh * 8 + m8) * 128;
    const int n0 = n_ * 128;
    const int tid = threadIdx.x;

    f32x16 acc[2][2] = {};

    gemm128(Xb, WT + (size_t)z * HDIM * HDIM, HDIM, HDIM, HDIM, m0, n0, smem, tid, acc);

    const int wv = tid >> 6, ln = tid & 63;
    const int wm = wv >> 1, wn = wv & 1;
    const int lane31 = ln & 31, laneHi = ln >> 5;
    u16* T = (u16*)smem;   // [128][136]

    if (z < 2) {
        const float pwsgn = (z == 0) ? (1.f / 512.f) : (-1.f / 512.f);
#pragma unroll
        for (int fn = 0; fn < 2; ++fn) {
            const int gc = n0 + wn * 64 + fn * 32 + lane31;
            const int ih = gc >> 1;
            const float invf = exp2f(-13.287712379549449f * (1.f / 512.f) * (float)ih);
            const float l2sv = log2f(((float)(2 * ih) + 409.6f) * (1.f / 1433.6f));
            const float sgn = (gc & 1) ? 1.f : -1.f;
#pragma unroll
            for (int fm = 0; fm < 2; ++fm) {
#pragma unroll
                for (int reg = 0; reg < 16; ++reg) {
                    const int ml = wm * 64 + fm * 32 + ROW32(reg, laneHi);
                    const int lpos = (m0 + ml) & (LDIM - 1);
                    float c = acc[fm][fn][reg];
                    float p = __shfl_xor(c, 1);   // even<->odd column partner
                    float sn, cs;
                    sincos_rev((float)lpos * invf, &sn, &cs);
                    float scl = exp2f((float)lpos * pwsgn * l2sv);
                    T[ml * 136 + wn * 64 + fn * 32 + lane31] = f2bf((c * cs + sgn * p * sn) * scl);
                }
            }
        }
    } else {
        // V: repack transposed  T[n_local][m_local]
#pragma unroll
        for (int fn = 0; fn < 2; ++fn)
#pragma unroll
            for (int fm = 0; fm < 2; ++fm)
#pragma unroll
                for (int reg = 0; reg < 16; ++reg)
                    T[(wn * 64 + fn * 32 + lane31) * 136 + wm * 64 + fm * 32 + ROW32(reg, laneHi)] =
                        f2bf(acc[fm][fn][reg]);
    }
    __syncthreads();

    const int row_ = tid >> 4, colb = (tid & 15) * 8;
    if (z < 2) {
        u16* Out = (z == 0) ? Qb : Kb;
#pragma unroll
        for (int g = 0; g < 8; ++g) {
            const int row = g * 16 + row_;
            s16x8 v = *(const s16x8*)&T[row * 136 + colb];
            *(s16x8*)&Out[(size_t)(m0 + row) * HDIM + n0 + colb] = v;
        }
    } else {
        const int b = m0 >> 11, l0 = m0 & (LDIM - 1);
#pragma unroll
        for (int g = 0; g < 8; ++g) {
            const int row = g * 16 + row_;   // n-local (d index)
            s16x8 v = *(const s16x8*)&T[row * 136 + colb];
            *(s16x8*)&Vt[((size_t)b * HDIM + n0 + row) * LDIM + l0 + colb] = v;
        }
    }
}

// ---------------------------------------------------------------------------
// K2a: W = exp(s)*gamma^|q-k| (bf16) + Z partials (fp32, deterministic).
// grid 2048: b = bid&7 (XCD-pinned). decode: mtH(2) nt(16) mt8(8)
// ---------------------------------------------------------------------------
__global__ __launch_bounds__(256) void qk_gemm(
    const u16* __restrict__ Q, const u16* __restrict__ Km,
    u16* __restrict__ Wm, float* __restrict__ Zp)
{
    __shared__ __align__(16) char smem[128 * 136 * 2];
    __shared__ float Zl[2][128];
    const int bid = blockIdx.x;
    const int b = bid & 7, t = bid >> 3;     // t in [0,256)
    const int mt8 = t & 7;
    const int w_ = t >> 3;                   // [0,32)
    const int nt = w_ & 15;
    const int mtH = w_ >> 4;
    const int m0 = (mtH * 8 + mt8) * 128;
    const int n0 = nt * 128;
    const int tid = threadIdx.x;

    f32x16 acc[2][2] = {};

    gemm128(Q + (size_t)b * LDIM * HDIM, Km + (size_t)b * LDIM * HDIM,
            HDIM, HDIM, HDIM, m0, n0, smem, tid, acc);

    const int wv = tid >> 6, ln = tid & 63;
    const int wm = wv >> 1, wn = wv & 1;
    const int lane31 = ln & 31, laneHi = ln >> 5;
    u16* T = (u16*)smem;   // [128][136]
    const float LOG2E = 1.4426950408889634f;
    const float LOG2G = -0.15200309344504997f;   // log2(0.9)

    float psum[2][16];
#pragma unroll
    for (int fm = 0; fm < 2; ++fm)
#pragma unroll
        for (int reg = 0; reg < 16; ++reg) psum[fm][reg] = 0.f;

#pragma unroll
    for (int fm = 0; fm < 2; ++fm) {
#pragma unroll
        for (int fn = 0; fn < 2; ++fn) {
            const int gk = n0 + wn * 64 + fn * 32 + lane31;
#pragma unroll
            for (int reg = 0; reg < 16; ++reg) {
                const int mloc = wm * 64 + fm * 32 + ROW32(reg, laneHi);
                const int gq = m0 + mloc;
                float t1 = acc[fm][fn][reg] * LOG2E;
                float e = exp2f(t1);
                int dd = gq - gk; dd = dd < 0 ? -dd : dd;
                psum[fm][reg] += e;
                T[mloc * 136 + wn * 64 + fn * 32 + lane31] =
                    f2bf(exp2f(t1 + (float)dd * LOG2G));
            }
        }
    }
    // reduce e-sums across the 32 column-lanes (bits 0-4; same-row lanes)
#pragma unroll
    for (int fm = 0; fm < 2; ++fm)
#pragma unroll
        for (int reg = 0; reg < 16; ++reg) {
            float s = psum[fm][reg];
            s += __shfl_xor(s, 1); s += __shfl_xor(s, 2);
            s += __shfl_xor(s, 4); s += __shfl_xor(s, 8);
            s += __shfl_xor(s, 16);
            if (lane31 == 0)
                Zl[wn][wm * 64 + fm * 32 + ROW32(reg, laneHi)] = s;
        }
    __syncthreads();

    const int row_ = tid >> 4, colb = (tid & 15) * 8;
#pragma unroll
    for (int g = 0; g < 8; ++g) {
        const int row = g * 16 + row_;
        s16x8 v = *(const s16x8*)&T[row * 136 + colb];
        *(s16x8*)&Wm[((size_t)b * LDIM + m0 + row) * LDIM + n0 + colb] = v;
    }
    if (tid < 128)
        Zp[((size_t)b * 16 + nt) * LDIM + m0 + tid] = Zl[0][tid] + Zl[1][tid];
}

// ---------------------------------------------------------------------------
// K2b: O = (W @ V) / Z  (fp32 out).  grid 1024: b=bid&7.
// decode: mtQ(4) nt(8) mt4(4)
// ---------------------------------------------------------------------------
__global__ __launch_bounds__(256) void pv_gemm(
    const u16* __restrict__ Wm, const u16* __restrict__ Vt,
    const float* __restrict__ Zp, float* __restrict__ Out)
{
    __shared__ __align__(16) char smem[128 * 136 * 2];
    __shared__ float Zinv[128];
    const int bid = blockIdx.x;
    const int b = bid & 7, t = bid >> 3;     // t in [0,128)
    const int mt4 = t & 3;
    const int w_ = t >> 2;                   // [0,32)
    const int nt = w_ & 7;
    const int mtQ = w_ >> 3;
    const int m0 = (mtQ * 4 + mt4) * 128;
    const int n0 = nt * 128;
    const int tid = threadIdx.x;

    if (tid < 128) {
        float zz = 0.f;
#pragma unroll
        for (int nb = 0; nb < 16; ++nb)
            zz += Zp[((size_t)b * 16 + nb) * LDIM + m0 + tid];
        Zinv[tid] = 1.0f / zz;
    }

    f32x16 acc[2][2] = {};

    gemm128(Wm + (size_t)b * LDIM * LDIM, Vt + (size_t)b * HDIM * LDIM,
            LDIM, LDIM, LDIM, m0, n0, smem, tid, acc);

    const int wv = tid >> 6, ln = tid & 63;
    const int wm = wv >> 1, wn = wv & 1;
    const int lane31 = ln & 31, laneHi = ln >> 5;
    float* Ob = Out + (size_t)b * LDIM * HDIM;
#pragma unroll
    for (int fm = 0; fm < 2; ++fm)
#pragma unroll
        for (int fn = 0; fn < 2; ++fn) {
            const int gn = n0 + wn * 64 + fn * 32 + lane31;
#pragma unroll
            for (int reg = 0; reg < 16; ++reg) {
                const int row = wm * 64 + fm * 32 + ROW32(reg, laneHi);
                Ob[(size_t)(m0 + row) * HDIM + gn] = acc[fm][fn][reg] * Zinv[row];
            }
        }
}

// ---------------------------------------------------------------------------
extern "C" void kernel_launch(void* const* d_in, const int* in_sizes, int n_in,
                              void* d_out, int out_size, void* d_ws, size_t ws_size,
                              hipStream_t stream)
{
    (void)in_sizes; (void)n_in; (void)out_size; (void)ws_size;
    const float* X  = (const float*)d_in[0];
    const float* Wq = (const float*)d_in[1];
    const float* Wk = (const float*)d_in[2];
    const float* Wv = (const float*)d_in[3];
    char* ws = (char*)d_ws;
    const size_t MB = 1024 * 1024;

    u16* Wmat = (u16*)ws;                 // phase2, aliases Xb+WT
    u16* Xb   = (u16*)ws;                 // phase1
    u16* WT   = (u16*)(ws + 32 * MB);     // phase1
    u16* Qb   = (u16*)(ws + 64 * MB);
    u16* Kb   = (u16*)(ws + 96 * MB);
    u16* Vt   = (u16*)(ws + 128 * MB);
    float* Zp = (float*)(ws + 160 * MB);

    cast_x<<<2048, 256, 0, stream>>>(X, Xb, MTOT * HDIM / 4);
    transw<<<dim3(16, 16, 3), 256, 0, stream>>>(Wq, Wk, Wv, WT);
    qkv_gemm<<<3072, 256, 0, stream>>>(Xb, WT, Qb, Kb, Vt);
    qk_gemm<<<2048, 256, 0, stream>>>(Qb, Kb, Wmat, Zp);
    pv_gemm<<<1024, 256, 0, stream>>>(Wmat, Vt, Zp, (float*)d_out);
}

// Round 5
// 350.509 us; speedup vs baseline: 1.5685x; 1.5685x over previous
//
#include <hip/hip_runtime.h>
#include <math.h>

// SimpleRetention bf16-MFMA pipeline, round 5.
// out = (softmax(QK^T) * gamma^|n-m|) @ V ; Q/K = xpos(X@W), V = X@Wv
// B=8 L=2048 H=Dh=1024.
//
// Round-5 change vs round-4 (one lever):
//  - LDS XOR-swizzle byte^=((row&7)<<4) on the staged tiles, applied
//    both-sides: inverse-swizzled GLD16 *source* slot (LDS dest stays linear,
//    required by global_load_lds) + swizzled ds_read_b128 fragment address.
//    Fixes the 32-lanes-per-2-slots bank conflict (8.9e7 conflict cycles).
//
// ws layout (161MB total; phase-aliased):
//   [0,64MB)    Wmat bf16 [8][2048][2048]   (phase2; aliases Xb+WT of phase1)
//   [0,32MB)    Xb  bf16 [16384][1024]      (phase1)
//   [32,38MB)   WT  bf16 [3][1024][1024]    (phase1, W transposed)
//   [64,96MB)   Qb  bf16 [16384][1024]
//   [96,128MB)  Kb  bf16 [16384][1024]
//   [128,160MB) Vt  bf16 [8][1024][2048]    (V transposed per batch)
//   [160,161MB) Zp  f32  [8][16][2048]      (softmax denom partials)

#define LDIM 2048
#define HDIM 1024
#define MTOT 16384

typedef unsigned short u16;
typedef __attribute__((ext_vector_type(16))) float f32x16;
typedef __attribute__((ext_vector_type(8))) short s16x8;

#define GLD16(gp, lp) __builtin_amdgcn_global_load_lds( \
    (const __attribute__((address_space(1))) void*)(gp), \
    (__attribute__((address_space(3))) void*)(lp), 16, 0, 0)

__device__ __forceinline__ u16 f2bf(float f) {
    unsigned u = __float_as_uint(f);
    return (u16)((u + 0x7FFFu + ((u >> 16) & 1u)) >> 16);
}

// sin/cos(ang) via f64 revolution reduction + HW v_sin/v_cos (rev input).
__device__ __forceinline__ void sincos_rev(float ang, float* sn, float* cs) {
    double dr = (double)ang * 0.15915494309189535;   // 1/(2*pi)
    dr -= __builtin_floor(dr);
    float fr = (float)dr;
    float s_, c_;
    asm("v_sin_f32 %0, %1" : "=v"(s_) : "v"(fr));
    asm("v_cos_f32 %0, %1" : "=v"(c_) : "v"(fr));
    *sn = s_; *cs = c_;
}

// C/D mapping for mfma_f32_32x32x16_bf16 (HW-verified m74/m101):
//   col = lane&31, row = (reg&3) + 8*(reg>>2) + 4*(lane>>5), reg in [0,16)
#define ROW32(reg, laneHi) (((reg) & 3) + 8 * ((reg) >> 2) + 4 * (laneHi))

// ---------------------------------------------------------------------------
// Shared 128x128 bf16 MFMA GEMM core. C = A x B^T, A:[*,lda], B:[*,ldb] rowmaj.
// 256 thr = 4 waves (2x2), each wave 64x64 = 2x2 frags of 32x32x16 MFMA.
// LDS: As[128][64] + Bs[128][64] bf16 = 32KB, XOR-swizzled (row&7)<<4.
// ---------------------------------------------------------------------------
__device__ __forceinline__ void gemm128(const u16* __restrict__ A, const u16* __restrict__ B,
                                        int lda, int ldb, int K, int m0, int n0,
                                        char* smem, int tid, f32x16 (*acc)[2])
{
    char* As = smem;
    char* Bs = smem + 128 * 128;
    const int wv = tid >> 6, ln = tid & 63;
    const int wm = wv >> 1, wn = wv & 1;
    const int lane31 = ln & 31, laneHi = ln >> 5;
    const int srow = wv * 8 + (ln >> 3);            // staging row (row&7 == ln>>3)
    const int scol = ((ln & 7) ^ (ln >> 3)) * 8;    // inverse-swizzled source col

    // incremental per-thread global source pointers (advance 64 elems/iter)
    const u16* ap[4];
    const u16* bp[4];
#pragma unroll
    for (int i = 0; i < 4; ++i) {
        ap[i] = A + (size_t)(m0 + i * 32 + srow) * lda + scol;
        bp[i] = B + (size_t)(n0 + i * 32 + srow) * ldb + scol;
    }

    // swizzled LDS fragment base byte offsets; per-ks XOR (ks<<5)
    int abyte[2], bbyte[2];
#pragma unroll
    for (int f = 0; f < 2; ++f) {
        const int row_a = wm * 64 + f * 32 + lane31;
        const int row_b = wn * 64 + f * 32 + lane31;
        const int slot = (laneHi ^ (lane31 & 7)) << 4;
        abyte[f] = row_a * 128 + slot;
        bbyte[f] = row_b * 128 + slot;
    }

    for (int k0 = 0; k0 < K; k0 += 64) {
        __syncthreads();   // all waves done reading previous tile
#pragma unroll
        for (int i = 0; i < 4; ++i) {
            GLD16(ap[i], As + (i * 32 + wv * 8) * 128);
            GLD16(bp[i], Bs + (i * 32 + wv * 8) * 128);
            ap[i] += 64; bp[i] += 64;
        }
        __syncthreads();   // tile resident
#pragma unroll
        for (int ks = 0; ks < 4; ++ks) {
            s16x8 af[2], bf[2];
#pragma unroll
            for (int f = 0; f < 2; ++f) {
                af[f] = *(const s16x8*)(As + (abyte[f] ^ (ks << 5)));
                bf[f] = *(const s16x8*)(Bs + (bbyte[f] ^ (ks << 5)));
            }
#pragma unroll
            for (int i = 0; i < 2; ++i)
#pragma unroll
                for (int j = 0; j < 2; ++j)
                    acc[i][j] = __builtin_amdgcn_mfma_f32_32x32x16_bf16(af[i], bf[j], acc[i][j], 0, 0, 0);
        }
    }
    __syncthreads();   // safe to reuse smem in epilogue
}

// ---------------------------------------------------------------------------
// prep: X -> bf16
// ---------------------------------------------------------------------------
__global__ __launch_bounds__(256) void cast_x(const float* __restrict__ X,
                                              u16* __restrict__ Xb, int n4)
{
    int i = blockIdx.x * 256 + threadIdx.x;
    const int stride = gridDim.x * 256;
    for (; i < n4; i += stride) {
        float4 v = ((const float4*)X)[i];
        ushort4 o = make_ushort4(f2bf(v.x), f2bf(v.y), f2bf(v.z), f2bf(v.w));
        ((ushort4*)Xb)[i] = o;
    }
}

// ---------------------------------------------------------------------------
// prep: W (1024x1024 f32, [k][n]) -> WT bf16 [n][k], for z in {Q,K,V}
// ---------------------------------------------------------------------------
__global__ __launch_bounds__(256) void transw(const float* __restrict__ Wq,
                                              const float* __restrict__ Wk,
                                              const float* __restrict__ Wv,
                                              u16* __restrict__ WT)
{
    __shared__ float L[64][65];
    const int z = blockIdx.z;
    const float* Wz = (z == 0) ? Wq : (z == 1) ? Wk : Wv;
    u16* Oz = WT + (size_t)z * HDIM * HDIM;
    const int k0 = blockIdx.y * 64, n0 = blockIdx.x * 64;
    const int t = threadIdx.x;
    const int r_ = t >> 4, c4 = (t & 15) * 4;
#pragma unroll
    for (int it = 0; it < 4; ++it) {
        const int row = it * 16 + r_;
        float4 v = *(const float4*)&Wz[(size_t)(k0 + row) * HDIM + n0 + c4];
        L[row][c4 + 0] = v.x; L[row][c4 + 1] = v.y;
        L[row][c4 + 2] = v.z; L[row][c4 + 3] = v.w;
    }
    __syncthreads();
#pragma unroll
    for (int it = 0; it < 4; ++it) {
        const int orow = it * 16 + r_;   // n-local
        ushort4 o = make_ushort4(f2bf(L[c4 + 0][orow]), f2bf(L[c4 + 1][orow]),
                                 f2bf(L[c4 + 2][orow]), f2bf(L[c4 + 3][orow]));
        *(ushort4*)&Oz[(size_t)(n0 + orow) * HDIM + k0 + c4] = o;
    }
}

// ---------------------------------------------------------------------------
// K1: {Q,K,V} = X@W, xpos fused (fp32) for Q/K, V stored transposed.
// 1D grid 3072, XCD-chunked. decode: xcd(8) | mh(2) n(8) z(3) m8(8)
// ---------------------------------------------------------------------------
__global__ __launch_bounds__(256) void qkv_gemm(
    const u16* __restrict__ Xb, const u16* __restrict__ WT,
    u16* __restrict__ Qb, u16* __restrict__ Kb, u16* __restrict__ Vt)
{
    __shared__ __align__(16) char smem[128 * 136 * 2];
    const int bid = blockIdx.x;
    const int xcd = bid & 7, t = bid >> 3;   // t in [0,384)
    const int m8 = t & 7;
    const int u_ = t >> 3;                   // [0,48)
    const int z  = u_ % 3;
    const int v_ = u_ / 3;                   // [0,16)
    const int n_ = v_ & 7;
    const int mh = v_ >> 3;
    const int m0 = (xcd * 16 + mh * 8 + m8) * 128;
    const int n0 = n_ * 128;
    const int tid = threadIdx.x;

    f32x16 acc[2][2] = {};

    gemm128(Xb, WT + (size_t)z * HDIM * HDIM, HDIM, HDIM, HDIM, m0, n0, smem, tid, acc);

    const int wv = tid >> 6, ln = tid & 63;
    const int wm = wv >> 1, wn = wv & 1;
    const int lane31 = ln & 31, laneHi = ln >> 5;
    u16* T = (u16*)smem;   // [128][136]

    if (z < 2) {
        const float pwsgn = (z == 0) ? (1.f / 512.f) : (-1.f / 512.f);
#pragma unroll
        for (int fn = 0; fn < 2; ++fn) {
            const int gc = n0 + wn * 64 + fn * 32 + lane31;
            const int ih = gc >> 1;
            const float invf = exp2f(-13.287712379549449f * (1.f / 512.f) * (float)ih);
            const float l2sv = log2f(((float)(2 * ih) + 409.6f) * (1.f / 1433.6f));
            const float sgn = (gc & 1) ? 1.f : -1.f;
#pragma unroll
            for (int fm = 0; fm < 2; ++fm) {
#pragma unroll
                for (int reg = 0; reg < 16; ++reg) {
                    const int ml = wm * 64 + fm * 32 + ROW32(reg, laneHi);
                    const int lpos = (m0 + ml) & (LDIM - 1);
                    float c = acc[fm][fn][reg];
                    float p = __shfl_xor(c, 1);   // even<->odd column partner
                    float sn, cs;
                    sincos_rev((float)lpos * invf, &sn, &cs);
                    float scl = exp2f((float)lpos * pwsgn * l2sv);
                    T[ml * 136 + wn * 64 + fn * 32 + lane31] = f2bf((c * cs + sgn * p * sn) * scl);
                }
            }
        }
    } else {
        // V: repack transposed  T[n_local][m_local]
#pragma unroll
        for (int fn = 0; fn < 2; ++fn)
#pragma unroll
            for (int fm = 0; fm < 2; ++fm)
#pragma unroll
                for (int reg = 0; reg < 16; ++reg)
                    T[(wn * 64 + fn * 32 + lane31) * 136 + wm * 64 + fm * 32 + ROW32(reg, laneHi)] =
                        f2bf(acc[fm][fn][reg]);
    }
    __syncthreads();

    const int row_ = tid >> 4, colb = (tid & 15) * 8;
    if (z < 2) {
        u16* Out = (z == 0) ? Qb : Kb;
#pragma unroll
        for (int g = 0; g < 8; ++g) {
            const int row = g * 16 + row_;
            s16x8 v = *(const s16x8*)&T[row * 136 + colb];
            *(s16x8*)&Out[(size_t)(m0 + row) * HDIM + n0 + colb] = v;
        }
    } else {
        const int b = m0 >> 11, l0 = m0 & (LDIM - 1);
#pragma unroll
        for (int g = 0; g < 8; ++g) {
            const int row = g * 16 + row_;   // n-local (d index)
            s16x8 v = *(const s16x8*)&T[row * 136 + colb];
            *(s16x8*)&Vt[((size_t)b * HDIM + n0 + row) * LDIM + l0 + colb] = v;
        }
    }
}

// ---------------------------------------------------------------------------
// K2a: W = exp(s)*gamma^|q-k| (bf16) + Z partials (fp32, deterministic).
// grid 2048: b = bid&7 (XCD-pinned). decode: mtH(2) nt(16) mt8(8)
// ---------------------------------------------------------------------------
__global__ __launch_bounds__(256) void qk_gemm(
    const u16* __restrict__ Q, const u16* __restrict__ Km,
    u16* __restrict__ Wm, float* __restrict__ Zp)
{
    __shared__ __align__(16) char smem[128 * 136 * 2];
    __shared__ float Zl[2][128];
    const int bid = blockIdx.x;
    const int b = bid & 7, t = bid >> 3;     // t in [0,256)
    const int mt8 = t & 7;
    const int w_ = t >> 3;                   // [0,32)
    const int nt = w_ & 15;
    const int mtH = w_ >> 4;
    const int m0 = (mtH * 8 + mt8) * 128;
    const int n0 = nt * 128;
    const int tid = threadIdx.x;

    f32x16 acc[2][2] = {};

    gemm128(Q + (size_t)b * LDIM * HDIM, Km + (size_t)b * LDIM * HDIM,
            HDIM, HDIM, HDIM, m0, n0, smem, tid, acc);

    const int wv = tid >> 6, ln = tid & 63;
    const int wm = wv >> 1, wn = wv & 1;
    const int lane31 = ln & 31, laneHi = ln >> 5;
    u16* T = (u16*)smem;   // [128][136]
    const float LOG2E = 1.4426950408889634f;
    const float LOG2G = -0.15200309344504997f;   // log2(0.9)

    float psum[2][16];
#pragma unroll
    for (int fm = 0; fm < 2; ++fm)
#pragma unroll
        for (int reg = 0; reg < 16; ++reg) psum[fm][reg] = 0.f;

#pragma unroll
    for (int fm = 0; fm < 2; ++fm) {
#pragma unroll
        for (int fn = 0; fn < 2; ++fn) {
            const int gk = n0 + wn * 64 + fn * 32 + lane31;
#pragma unroll
            for (int reg = 0; reg < 16; ++reg) {
                const int mloc = wm * 64 + fm * 32 + ROW32(reg, laneHi);
                const int gq = m0 + mloc;
                float t1 = acc[fm][fn][reg] * LOG2E;
                float e = exp2f(t1);
                int dd = gq - gk; dd = dd < 0 ? -dd : dd;
                psum[fm][reg] += e;
                T[mloc * 136 + wn * 64 + fn * 32 + lane31] =
                    f2bf(exp2f(t1 + (float)dd * LOG2G));
            }
        }
    }
    // reduce e-sums across the 32 column-lanes (bits 0-4; same-row lanes)
#pragma unroll
    for (int fm = 0; fm < 2; ++fm)
#pragma unroll
        for (int reg = 0; reg < 16; ++reg) {
            float s = psum[fm][reg];
            s += __shfl_xor(s, 1); s += __shfl_xor(s, 2);
            s += __shfl_xor(s, 4); s += __shfl_xor(s, 8);
            s += __shfl_xor(s, 16);
            if (lane31 == 0)
                Zl[wn][wm * 64 + fm * 32 + ROW32(reg, laneHi)] = s;
        }
    __syncthreads();

    const int row_ = tid >> 4, colb = (tid & 15) * 8;
#pragma unroll
    for (int g = 0; g < 8; ++g) {
        const int row = g * 16 + row_;
        s16x8 v = *(const s16x8*)&T[row * 136 + colb];
        *(s16x8*)&Wm[((size_t)b * LDIM + m0 + row) * LDIM + n0 + colb] = v;
    }
    if (tid < 128)
        Zp[((size_t)b * 16 + nt) * LDIM + m0 + tid] = Zl[0][tid] + Zl[1][tid];
}

// ---------------------------------------------------------------------------
// K2b: O = (W @ V) / Z  (fp32 out).  grid 1024: b=bid&7.
// decode: mtQ(4) nt(8) mt4(4)
// ---------------------------------------------------------------------------
__global__ __launch_bounds__(256) void pv_gemm(
    const u16* __restrict__ Wm, const u16* __restrict__ Vt,
    const float* __restrict__ Zp, float* __restrict__ Out)
{
    __shared__ __align__(16) char smem[128 * 136 * 2];
    __shared__ float Zinv[128];
    const int bid = blockIdx.x;
    const int b = bid & 7, t = bid >> 3;     // t in [0,128)
    const int mt4 = t & 3;
    const int w_ = t >> 2;                   // [0,32)
    const int nt = w_ & 7;
    const int mtQ = w_ >> 3;
    const int m0 = (mtQ * 4 + mt4) * 128;
    const int n0 = nt * 128;
    const int tid = threadIdx.x;

    if (tid < 128) {
        float zz = 0.f;
#pragma unroll
        for (int nb = 0; nb < 16; ++nb)
            zz += Zp[((size_t)b * 16 + nb) * LDIM + m0 + tid];
        Zinv[tid] = 1.0f / zz;
    }

    f32x16 acc[2][2] = {};

    gemm128(Wm + (size_t)b * LDIM * LDIM, Vt + (size_t)b * HDIM * LDIM,
            LDIM, LDIM, LDIM, m0, n0, smem, tid, acc);

    const int wv = tid >> 6, ln = tid & 63;
    const int wm = wv >> 1, wn = wv & 1;
    const int lane31 = ln & 31, laneHi = ln >> 5;
    float* Ob = Out + (size_t)b * LDIM * HDIM;
#pragma unroll
    for (int fm = 0; fm < 2; ++fm)
#pragma unroll
        for (int fn = 0; fn < 2; ++fn) {
            const int gn = n0 + wn * 64 + fn * 32 + lane31;
#pragma unroll
            for (int reg = 0; reg < 16; ++reg) {
                const int row = wm * 64 + fm * 32 + ROW32(reg, laneHi);
                Ob[(size_t)(m0 + row) * HDIM + gn] = acc[fm][fn][reg] * Zinv[row];
            }
        }
}

// ---------------------------------------------------------------------------
extern "C" void kernel_launch(void* const* d_in, const int* in_sizes, int n_in,
                              void* d_out, int out_size, void* d_ws, size_t ws_size,
                              hipStream_t stream)
{
    (void)in_sizes; (void)n_in; (void)out_size; (void)ws_size;
    const float* X  = (const float*)d_in[0];
    const float* Wq = (const float*)d_in[1];
    const float* Wk = (const float*)d_in[2];
    const float* Wv = (const float*)d_in[3];
    char* ws = (char*)d_ws;
    const size_t MB = 1024 * 1024;

    u16* Wmat = (u16*)ws;                 // phase2, aliases Xb+WT
    u16* Xb   = (u16*)ws;                 // phase1
    u16* WT   = (u16*)(ws + 32 * MB);     // phase1
    u16* Qb   = (u16*)(ws + 64 * MB);
    u16* Kb   = (u16*)(ws + 96 * MB);
    u16* Vt   = (u16*)(ws + 128 * MB);
    float* Zp = (float*)(ws + 160 * MB);

    cast_x<<<2048, 256, 0, stream>>>(X, Xb, MTOT * HDIM / 4);
    transw<<<dim3(16, 16, 3), 256, 0, stream>>>(Wq, Wk, Wv, WT);
    qkv_gemm<<<3072, 256, 0, stream>>>(Xb, WT, Qb, Kb, Vt);
    qk_gemm<<<2048, 256, 0, stream>>>(Qb, Kb, Wmat, Zp);
    pv_gemm<<<1024, 256, 0, stream>>>(Wmat, Vt, Zp, (float*)d_out);
}